// Round 1
// baseline (342.097 us; speedup 1.0000x reference)
//
#include <hip/hip_runtime.h>

#define NC      53
#define HW_BITS 18            // H*W = 512*512 = 2^18
#define BLK     256
#define PPT     4             // pixels per thread (float4)

// Fused focal tree-min loss — CLASS-SERIALIZED + SOFTWARE-PIPELINED.
// Tree (fixed): parent2[l]=41+l%9; parent1[s]=50+s%3; (l%9)%3 == l%3.
// multi_hot(lab) = {lab, 41+lab%9, 50+lab%3}.
//
// History: R1-R4 (53 concurrent read streams) plateaued at 2.47 TB/s (DRAM
// row thrash). R5 serialized into ~6-stream subtree groups -> ~4.5 TB/s, but
// `#pragma unroll 1` made each group a {issue 6 loads -> vmcnt(0) -> compute}
// latency bubble (no compiler modulo scheduling) with only 4 waves/SIMD to
// cover it. R6 (this): flatten the 9 subtree groups into a static sequence
// with TWO register buffers: load(g+1) issues before compute(g), so the
// ~1000cy HBM latency hides under the ~600cy focal compute of the previous
// group, while stream count stays <=12 (far from the thrash regime).
//
// Per element, t=mh, y = mh ? -x : x:  term = sigmoid(y)^2 * softplus(y)
//   l2 = log2(1+exp2(-log2e*|y|)):
//   spp = max(y,0)+l2*ln2 ; spn = max(-y,0)+l2*ln2 ; term = exp2(-2log2e*spn)*spp

__device__ __forceinline__ float focal_term(float y) {
    const float a   = __builtin_amdgcn_exp2f(-1.4426950408889634f * fabsf(y));
    const float l2  = __builtin_amdgcn_logf(1.0f + a);           // log2(1+a)
    const float spp = fmaf(l2, 0.6931471805599453f, fmaxf(y, 0.0f));
    const float spn = fmaf(l2, 0.6931471805599453f, fmaxf(-y, 0.0f));
    const float w   = __builtin_amdgcn_exp2f(-2.8853900817779268f * spn); // sig(y)^2
    return w * spp;
}

// ---- one subtree group = second-level node 41+R plus its leaves R+9j ----

template<int R>
__device__ __forceinline__ void load_group(const float4* __restrict__ p,
                                           float4 (&buf)[6]) {
    // class stride in float4 units: 2^16
    buf[0] = p[(size_t)(41 + R) << 16];          // second-level node row
    buf[1] = p[(size_t)(R +  0) << 16];
    buf[2] = p[(size_t)(R +  9) << 16];
    buf[3] = p[(size_t)(R + 18) << 16];
    buf[4] = p[(size_t)(R + 27) << 16];
    if constexpr (R + 36 < 41) buf[5] = p[(size_t)(R + 36) << 16];
}

template<int R>
__device__ __forceinline__ void compute_group(const float4 (&buf)[6],
    const int (&labv)[4], const int (&a1v)[4],
    const float (&pf)[4],                 // pfir row of this subtree's parent1
    float (&fm)[4], float (&acc)[4])
{
    const float ps[4] = {buf[0].x, buf[0].y, buf[0].z, buf[0].w};
    float manc[4], smax[4];
    #pragma unroll
    for (int k = 0; k < 4; ++k) {
        manc[k] = fminf(ps[k], pf[k]);           // min over leaf-ancestors
        smax[k] = ps[k];
    }

    constexpr int NL = (R + 36 < 41) ? 5 : 4;    // leaves in this subtree
    #pragma unroll
    for (int j = 0; j < NL; ++j) {
        const int l = R + 9 * j;
        const float xv[4] = {buf[1+j].x, buf[1+j].y, buf[1+j].z, buf[1+j].w};
        #pragma unroll
        for (int k = 0; k < 4; ++k) {
            const float x = xv[k];
            const float y = (l == labv[k]) ? -fminf(x, manc[k]) : x;
            acc[k] += focal_term(y);
            smax[k] = fmaxf(smax[k], x);
        }
    }

    // node 41+R: mh -> -manc, else desc-max
    #pragma unroll
    for (int k = 0; k < 4; ++k) {
        const float y = (a1v[k] == 41 + R) ? -manc[k] : smax[k];
        acc[k] += focal_term(y);
        fm[k] = fmaxf(fm[k], smax[k]);
    }
}

template<int F>
__device__ __forceinline__ void emit_first(const float (&pf)[4],
    const int (&a3v)[4], const float (&fm)[4], float (&acc)[4])
{
    #pragma unroll
    for (int k = 0; k < 4; ++k) {
        const float y = (a3v[k] == F) ? -pf[k] : fm[k];
        acc[k] += focal_term(y);
    }
}

__global__ __launch_bounds__(256, 4) void focal_tree_kernel(
    const float* __restrict__ cls,
    const int4*  __restrict__ label4,
    float* __restrict__ out, float scale)
{
    const int tid = blockIdx.x * BLK + threadIdx.x;      // 4-pixel group index
    const int n0  = tid << 2;
    const int b   = n0 >> HW_BITS;                       // uniform within block
    const int hw  = n0 & ((1 << HW_BITS) - 1);
    const float4* p = (const float4*)(cls + (((size_t)b * NC) << HW_BITS)) + (hw >> 2);

    const int4 lab = label4[tid];
    const int labv[4] = {lab.x, lab.y, lab.z, lab.w};
    int a1v[4], a3v[4];
    #pragma unroll
    for (int k = 0; k < 4; ++k) {
        a1v[k] = 41 + labv[k] % 9;                       // second-level ancestor id
        a3v[k] = labv[k] % 3;                            // first-level ancestor idx
    }

    // first-level rows (50..52) — resident across the whole sweep
    float pfir[3][4];
    #pragma unroll
    for (int f = 0; f < 3; ++f) {
        const float4 v = p[(size_t)(50 + f) << 16];
        pfir[f][0]=v.x; pfir[f][1]=v.y; pfir[f][2]=v.z; pfir[f][3]=v.w;
    }

    float acc[4] = {0.f, 0.f, 0.f, 0.f};
    float fm[4];
    float4 bufA[6], bufB[6];

    // Static pipeline: group order g0..g8 = (f,r):
    // (0,0)(0,3)(0,6) (1,1)(1,4)(1,7) (2,2)(2,5)(2,8)
    load_group<0>(p, bufA);                              // g0
    load_group<3>(p, bufB);                              // g1 (prefetch)

    // ---- f = 0 ----
    #pragma unroll
    for (int k = 0; k < 4; ++k) fm[k] = pfir[0][k];
    compute_group<0>(bufA, labv, a1v, pfir[0], fm, acc); // g0
    load_group<6>(p, bufA);                              // g2
    compute_group<3>(bufB, labv, a1v, pfir[0], fm, acc); // g1
    load_group<1>(p, bufB);                              // g3
    compute_group<6>(bufA, labv, a1v, pfir[0], fm, acc); // g2
    emit_first<0>(pfir[0], a3v, fm, acc);

    // ---- f = 1 ----
    #pragma unroll
    for (int k = 0; k < 4; ++k) fm[k] = pfir[1][k];
    load_group<4>(p, bufA);                              // g4
    compute_group<1>(bufB, labv, a1v, pfir[1], fm, acc); // g3
    load_group<7>(p, bufB);                              // g5
    compute_group<4>(bufA, labv, a1v, pfir[1], fm, acc); // g4
    load_group<2>(p, bufA);                              // g6
    compute_group<7>(bufB, labv, a1v, pfir[1], fm, acc); // g5
    emit_first<1>(pfir[1], a3v, fm, acc);

    // ---- f = 2 ----
    #pragma unroll
    for (int k = 0; k < 4; ++k) fm[k] = pfir[2][k];
    load_group<5>(p, bufB);                              // g7
    compute_group<2>(bufA, labv, a1v, pfir[2], fm, acc); // g6
    load_group<8>(p, bufA);                              // g8
    compute_group<5>(bufB, labv, a1v, pfir[2], fm, acc); // g7
    compute_group<8>(bufA, labv, a1v, pfir[2], fm, acc); // g8
    emit_first<2>(pfir[2], a3v, fm, acc);

    // ---- reduce: 4 px -> wave shuffle -> block -> one atomic ----
    float v = (acc[0] + acc[1]) + (acc[2] + acc[3]);
    #pragma unroll
    for (int off = 32; off > 0; off >>= 1)
        v += __shfl_down(v, off, 64);

    __shared__ float wsum[4];
    const int lane = threadIdx.x & 63;
    const int wid  = threadIdx.x >> 6;
    if (lane == 0) wsum[wid] = v;
    __syncthreads();
    if (threadIdx.x == 0) {
        const float s = (wsum[0] + wsum[1]) + (wsum[2] + wsum[3]);
        atomicAdd(out, s * scale);
    }
}

extern "C" void kernel_launch(void* const* d_in, const int* in_sizes, int n_in,
                              void* d_out, int out_size, void* d_ws, size_t ws_size,
                              hipStream_t stream) {
    const float* cls    = (const float*)d_in[0];
    const int4*  label4 = (const int4*)d_in[1];
    float* out = (float*)d_out;

    const int npix  = in_sizes[1];               // 4*512*512 = 1,048,576
    const float scale = (float)(1.0 / ((double)npix * (double)NC));

    hipMemsetAsync(d_out, 0, sizeof(float), stream);   // d_out poisoned 0xAA

    const int blocks = npix / (BLK * PPT);       // 1024
    focal_tree_kernel<<<blocks, BLK, 0, stream>>>(cls, label4, out, scale);
}

// Round 3
// 311.230 us; speedup vs baseline: 1.0992x; 1.0992x over previous
//
#include <hip/hip_runtime.h>

#define NC      53
#define HW_BITS 18            // H*W = 512*512 = 2^18
#define BLK     256
#define PPT     2             // pixels per thread (float2)

// Fused focal tree-min loss — CLASS-SERIALIZED + SOFTWARE-PIPELINED, PPT=2.
// Tree (fixed): parent2[l]=41+l%9; parent1[s]=50+s%3; (l%9)%3 == l%3.
// multi_hot(lab) = {lab, 41+lab%9, 50+lab%3}.
//
// History:
//  R1-R4: 53 concurrent read streams -> 2.47 TB/s (DRAM row thrash).
//  R5: subtree-group serialization (~6 streams) -> 4.4 TB/s, 51us kernel,
//      but each group is a {6 loads -> vmcnt -> compute} latency bubble and
//      grid (1024 blk @ PPT=4) caps occupancy at 16 waves/CU.
//  R6: 2-deep register pipeline @ PPT=4 + __launch_bounds__(256,4):
//      REGRESSED 143us kernel. VGPR_Count=64 cap << ~110 live regs ->
//      WRITE_SIZE=77MB scratch spills. Bounds clause strangled it.
//  R7: same pipeline, PPT=2 (float2): live set ~60 VGPRs fits 64-reg
//      allocation with plain __launch_bounds__(256); grid 2048 blocks ->
//      8 blocks/CU (32 waves/CU) TLP on top of the 2-deep pipeline.
//      (R7 bench attempt died to a container-acquisition failure; this is
//      the same kernel resubmitted.)
//
// Per element, t=mh, y = mh ? -x : x:  term = sigmoid(y)^2 * softplus(y)
//   l2 = log2(1+exp2(-log2e*|y|)):
//   spp = max(y,0)+l2*ln2 ; spn = max(-y,0)+l2*ln2 ; term = exp2(-2log2e*spn)*spp

__device__ __forceinline__ float focal_term(float y) {
    const float a   = __builtin_amdgcn_exp2f(-1.4426950408889634f * fabsf(y));
    const float l2  = __builtin_amdgcn_logf(1.0f + a);           // log2(1+a)
    const float spp = fmaf(l2, 0.6931471805599453f, fmaxf(y, 0.0f));
    const float spn = fmaf(l2, 0.6931471805599453f, fmaxf(-y, 0.0f));
    const float w   = __builtin_amdgcn_exp2f(-2.8853900817779268f * spn); // sig(y)^2
    return w * spp;
}

// ---- one subtree group = second-level node 41+R plus its leaves R+9j ----
// class stride in float2 units: 2^17

template<int R>
__device__ __forceinline__ void load_group(const float2* __restrict__ p,
                                           float2 (&buf)[6]) {
    buf[0] = p[(size_t)(41 + R) << 17];          // second-level node row
    buf[1] = p[(size_t)(R +  0) << 17];
    buf[2] = p[(size_t)(R +  9) << 17];
    buf[3] = p[(size_t)(R + 18) << 17];
    buf[4] = p[(size_t)(R + 27) << 17];
    if constexpr (R + 36 < 41) buf[5] = p[(size_t)(R + 36) << 17];
}

template<int R>
__device__ __forceinline__ void compute_group(const float2 (&buf)[6],
    const int (&labv)[2], const int (&a1v)[2],
    const float (&pf)[2],                 // pfir row of this subtree's parent1
    float (&fm)[2], float (&acc)[2])
{
    const float ps[2] = {buf[0].x, buf[0].y};
    float manc[2], smax[2];
    #pragma unroll
    for (int k = 0; k < 2; ++k) {
        manc[k] = fminf(ps[k], pf[k]);           // min over leaf-ancestors
        smax[k] = ps[k];
    }

    constexpr int NL = (R + 36 < 41) ? 5 : 4;    // leaves in this subtree
    #pragma unroll
    for (int j = 0; j < NL; ++j) {
        const int l = R + 9 * j;
        const float xv[2] = {buf[1+j].x, buf[1+j].y};
        #pragma unroll
        for (int k = 0; k < 2; ++k) {
            const float x = xv[k];
            const float y = (l == labv[k]) ? -fminf(x, manc[k]) : x;
            acc[k] += focal_term(y);
            smax[k] = fmaxf(smax[k], x);
        }
    }

    // node 41+R: mh -> -manc, else desc-max
    #pragma unroll
    for (int k = 0; k < 2; ++k) {
        const float y = (a1v[k] == 41 + R) ? -manc[k] : smax[k];
        acc[k] += focal_term(y);
        fm[k] = fmaxf(fm[k], smax[k]);
    }
}

template<int F>
__device__ __forceinline__ void emit_first(const float (&pf)[2],
    const int (&a3v)[2], const float (&fm)[2], float (&acc)[2])
{
    #pragma unroll
    for (int k = 0; k < 2; ++k) {
        const float y = (a3v[k] == F) ? -pf[k] : fm[k];
        acc[k] += focal_term(y);
    }
}

__global__ __launch_bounds__(256) void focal_tree_kernel(
    const float* __restrict__ cls,
    const int2*  __restrict__ label2,
    float* __restrict__ out, float scale)
{
    const int tid = blockIdx.x * BLK + threadIdx.x;      // 2-pixel group index
    const int n0  = tid << 1;
    const int b   = n0 >> HW_BITS;                       // uniform within block
    const int hw  = n0 & ((1 << HW_BITS) - 1);
    const float2* p = (const float2*)(cls + (((size_t)b * NC) << HW_BITS)) + (hw >> 1);

    const int2 lab = label2[tid];
    const int labv[2] = {lab.x, lab.y};
    int a1v[2], a3v[2];
    #pragma unroll
    for (int k = 0; k < 2; ++k) {
        a1v[k] = 41 + labv[k] % 9;                       // second-level ancestor id
        a3v[k] = labv[k] % 3;                            // first-level ancestor idx
    }

    // first-level rows (50..52) — resident across the whole sweep
    float pfir[3][2];
    #pragma unroll
    for (int f = 0; f < 3; ++f) {
        const float2 v = p[(size_t)(50 + f) << 17];
        pfir[f][0] = v.x; pfir[f][1] = v.y;
    }

    float acc[2] = {0.f, 0.f};
    float fm[2];
    float2 bufA[6], bufB[6];

    // Static pipeline: group order g0..g8 = (f,r):
    // (0,0)(0,3)(0,6) (1,1)(1,4)(1,7) (2,2)(2,5)(2,8)
    load_group<0>(p, bufA);                              // g0
    load_group<3>(p, bufB);                              // g1 (prefetch)

    // ---- f = 0 ----
    #pragma unroll
    for (int k = 0; k < 2; ++k) fm[k] = pfir[0][k];
    compute_group<0>(bufA, labv, a1v, pfir[0], fm, acc); // g0
    load_group<6>(p, bufA);                              // g2
    compute_group<3>(bufB, labv, a1v, pfir[0], fm, acc); // g1
    load_group<1>(p, bufB);                              // g3
    compute_group<6>(bufA, labv, a1v, pfir[0], fm, acc); // g2
    emit_first<0>(pfir[0], a3v, fm, acc);

    // ---- f = 1 ----
    #pragma unroll
    for (int k = 0; k < 2; ++k) fm[k] = pfir[1][k];
    load_group<4>(p, bufA);                              // g4
    compute_group<1>(bufB, labv, a1v, pfir[1], fm, acc); // g3
    load_group<7>(p, bufB);                              // g5
    compute_group<4>(bufA, labv, a1v, pfir[1], fm, acc); // g4
    load_group<2>(p, bufA);                              // g6
    compute_group<7>(bufB, labv, a1v, pfir[1], fm, acc); // g5
    emit_first<1>(pfir[1], a3v, fm, acc);

    // ---- f = 2 ----
    #pragma unroll
    for (int k = 0; k < 2; ++k) fm[k] = pfir[2][k];
    load_group<5>(p, bufB);                              // g7
    compute_group<2>(bufA, labv, a1v, pfir[2], fm, acc); // g6
    load_group<8>(p, bufA);                              // g8
    compute_group<5>(bufB, labv, a1v, pfir[2], fm, acc); // g7
    compute_group<8>(bufA, labv, a1v, pfir[2], fm, acc); // g8
    emit_first<2>(pfir[2], a3v, fm, acc);

    // ---- reduce: 2 px -> wave shuffle -> block -> one atomic ----
    float v = acc[0] + acc[1];
    #pragma unroll
    for (int off = 32; off > 0; off >>= 1)
        v += __shfl_down(v, off, 64);

    __shared__ float wsum[4];
    const int lane = threadIdx.x & 63;
    const int wid  = threadIdx.x >> 6;
    if (lane == 0) wsum[wid] = v;
    __syncthreads();
    if (threadIdx.x == 0) {
        const float s = (wsum[0] + wsum[1]) + (wsum[2] + wsum[3]);
        atomicAdd(out, s * scale);
    }
}

extern "C" void kernel_launch(void* const* d_in, const int* in_sizes, int n_in,
                              void* d_out, int out_size, void* d_ws, size_t ws_size,
                              hipStream_t stream) {
    const float* cls    = (const float*)d_in[0];
    const int2*  label2 = (const int2*)d_in[1];
    float* out = (float*)d_out;

    const int npix  = in_sizes[1];               // 4*512*512 = 1,048,576
    const float scale = (float)(1.0 / ((double)npix * (double)NC));

    hipMemsetAsync(d_out, 0, sizeof(float), stream);   // d_out poisoned 0xAA

    const int blocks = npix / (BLK * PPT);       // 2048
    focal_tree_kernel<<<blocks, BLK, 0, stream>>>(cls, label2, out, scale);
}